// Round 5
// baseline (65.243 us; speedup 1.0000x reference)
//
#include <hip/hip_runtime.h>

// Problem constants: N=512, L=16, HOP=8, M=8, C=2, K=6000
#define NN   512
#define LL   16
#define MM   8
#define CC   2
#define KK   6000
#define TT   ((KK - 1) * 8 + 16)      // 48008
#define KW   64                       // k-columns per block (256B, 64B-aligned tiles)
#define NCH  32                       // n-rows per chunk (8 waves x 4 rows)
#define NC   (NN / NCH)               // 16 chunks
#define ROWB (KK * 4)                 // 24000 bytes per n-row (64B aligned!)
#define TENS_B (NCH * KW * 4)         // 8192 B per tensor per buffer
#define BUF_B  (3 * TENS_B)           // 24576 B per buffer

typedef __attribute__((address_space(3))) void       lds_v;
typedef __attribute__((address_space(1))) const void glob_v;

// 512 threads = 8 waves, k = kb*64 + lane. Wave-self-sufficient DMA pipeline:
// wave wq issues exactly 3 global_load_lds per chunk (inputs/m0/m1, its own
// 4-row group) and consumes only those rows -> NO barriers in the main loop.
// Counted s_waitcnt vmcnt(3) keeps the next chunk's 3 loads in flight while
// computing the current chunk (T3+T4). W read via wave-uniform scalar loads
// (lgkmcnt path, doesn't disturb the vmcnt count). Tree-reduce 8 waves ->
// wave 0, in-register overlap-add, 2-term commutative seam atomics.
__global__ __launch_bounds__(512, 6) void decoder_dma_kernel(
    const float* __restrict__ inputs,    // [M, N, K]
    const float* __restrict__ est_mask,  // [M, C, N, K]
    const float* __restrict__ W,         // [N, L]
    float* __restrict__ out)             // [M, C, T], pre-zeroed
{
    __shared__ __align__(16) char lds[2 * BUF_B];   // 48 KB -> 3 blocks/CU

    const int tid = threadIdx.x;
    const int t   = tid & 63;                        // lane = k within tile
    const int wq  = __builtin_amdgcn_readfirstlane(tid >> 6);  // wave id 0..7
    const int kb  = blockIdx.x;                      // 0..93
    const int m   = blockIdx.y;                      // 0..7

    // per-lane DMA source offset: lane covers row (t>>4) of the wave's 4-row
    // group, 16B k-slice (t&15). Clamp column for the kb=93 tail (those
    // lanes' results are discarded by the k<KK guard in the epilogue).
    const int lane_r = t >> 4;
    int cb = kb * 256 + (t & 15) * 16;
    if (cb > ROWB - 16) cb = ROWB - 16;
    const size_t lane_off = (size_t)lane_r * ROWB + cb;

    const char* tb0 = (const char*)inputs   + (size_t)m * NN * ROWB;
    const char* tb1 = (const char*)est_mask + (size_t)(m * CC) * NN * ROWB;
    const char* tb2 = tb1 + (size_t)NN * ROWB;

    char* dst_base = lds + wq * 1024;   // wave's 4-row (1KB) slot per tensor

    // 3 DMA instructions per chunk per wave: 1KB each, linear [4 rows][256B].
    auto issue = [&](int c, int bsel) {
        const size_t rowoff = (size_t)(c * NCH + wq * 4) * ROWB + lane_off;
        char* bb = dst_base + bsel * BUF_B;
        __builtin_amdgcn_global_load_lds((glob_v*)(tb0 + rowoff), (lds_v*)(bb),              16, 0, 0);
        __builtin_amdgcn_global_load_lds((glob_v*)(tb1 + rowoff), (lds_v*)(bb + TENS_B),     16, 0, 0);
        __builtin_amdgcn_global_load_lds((glob_v*)(tb2 + rowoff), (lds_v*)(bb + 2 * TENS_B), 16, 0, 0);
    };

    float acc0[LL], acc1[LL];
    #pragma unroll
    for (int l = 0; l < LL; ++l) { acc0[l] = 0.f; acc1[l] = 0.f; }

    issue(0, 0);

    for (int c = 0; c < NC; ++c) {
        if (c + 1 < NC) {
            issue(c + 1, (c + 1) & 1);
            // outstanding: [chunk c: 3][chunk c+1: 3] -> wait until <=3 left,
            // i.e. chunk c landed, c+1 still in flight across the compute.
            asm volatile("s_waitcnt vmcnt(3)" ::: "memory");
        } else {
            asm volatile("s_waitcnt vmcnt(0)" ::: "memory");
        }
        __builtin_amdgcn_sched_barrier(0);   // rule-18 insurance: no hoisting

        const float* Lb = (const float*)(lds + (c & 1) * BUF_B + wq * 1024);

        #pragma unroll
        for (int rr = 0; rr < 4; ++rr) {
            const int n = c * NCH + wq * 4 + rr;     // wave-uniform -> s_load W
            float wv[LL];
            *reinterpret_cast<float4*>(&wv[0])  = *(const float4*)(W + n * LL + 0);
            *reinterpret_cast<float4*>(&wv[4])  = *(const float4*)(W + n * LL + 4);
            *reinterpret_cast<float4*>(&wv[8])  = *(const float4*)(W + n * LL + 8);
            *reinterpret_cast<float4*>(&wv[12]) = *(const float4*)(W + n * LL + 12);

            const float xin = Lb[rr * 64 + t];
            const float xm0 = Lb[(TENS_B / 4) + rr * 64 + t];
            const float xm1 = Lb[(2 * TENS_B / 4) + rr * 64 + t];
            const float x0 = xin * xm0;
            const float x1 = xin * xm1;
            #pragma unroll
            for (int l = 0; l < LL; ++l) {
                acc0[l] = fmaf(x0, wv[l], acc0[l]);
                acc1[l] = fmaf(x1, wv[l], acc1[l]);
            }
        }
    }

    // ---- all waves done (own DMA drained); safe to reuse LDS ----
    __syncthreads();

    // ---- tree-reduce 8 waves -> wave 0 (stride 33 -> 2-way = free) ----
    float* sm = (float*)lds;
    if (wq >= 4) {
        float* d = &sm[((wq - 4) * 64 + t) * 33];
        #pragma unroll
        for (int l = 0; l < LL; ++l) { d[l] = acc0[l]; d[16 + l] = acc1[l]; }
    }
    __syncthreads();
    if (wq < 4) {
        const float* s = &sm[(wq * 64 + t) * 33];
        #pragma unroll
        for (int l = 0; l < LL; ++l) { acc0[l] += s[l]; acc1[l] += s[16 + l]; }
    }
    __syncthreads();
    if (wq == 2 || wq == 3) {
        float* d = &sm[((wq - 2) * 64 + t) * 33];
        #pragma unroll
        for (int l = 0; l < LL; ++l) { d[l] = acc0[l]; d[16 + l] = acc1[l]; }
    }
    __syncthreads();
    if (wq < 2) {
        const float* s = &sm[(wq * 64 + t) * 33];
        #pragma unroll
        for (int l = 0; l < LL; ++l) { acc0[l] += s[l]; acc1[l] += s[16 + l]; }
    }
    __syncthreads();
    if (wq == 1) {
        float* d = &sm[t * 33];
        #pragma unroll
        for (int l = 0; l < LL; ++l) { d[l] = acc0[l]; d[16 + l] = acc1[l]; }
    }
    __syncthreads();

    if (wq == 0) {
        {
            const float* s = &sm[t * 33];
            #pragma unroll
            for (int l = 0; l < LL; ++l) { acc0[l] += s[l]; acc1[l] += s[16 + l]; }
        }

        // ---- overlap-and-add: out[8k+j] = lo_k[j] + hi_{k-1}[j] ----
        const int k = kb * KW + t;
        float ph0[8], ph1[8];
        #pragma unroll
        for (int j = 0; j < 8; ++j) {
            ph0[j] = __shfl_up(acc0[8 + j], 1);
            ph1[j] = __shfl_up(acc1[8 + j], 1);
        }

        if (k < KK) {
            float* o0 = out + ((size_t)m * CC + 0) * TT + 8 * k;
            float* o1 = out + ((size_t)m * CC + 1) * TT + 8 * k;

            if (t == 0) {
                // previous frame owned by another block -> atomic (zeroed base)
                #pragma unroll
                for (int j = 0; j < 8; ++j) {
                    atomicAdd(&o0[j], acc0[j]);
                    atomicAdd(&o1[j], acc1[j]);
                }
            } else {
                #pragma unroll
                for (int j = 0; j < 8; ++j) {
                    o0[j] = acc0[j] + ph0[j];
                    o1[j] = acc1[j] + ph1[j];
                }
            }
            if (t == 63 || k == KK - 1) {
                // hi half consumed by next block (or the tail) -> atomic
                #pragma unroll
                for (int j = 0; j < 8; ++j) {
                    atomicAdd(&o0[8 + j], acc0[8 + j]);
                    atomicAdd(&o1[8 + j], acc1[8 + j]);
                }
            }
        }
    }
}

extern "C" void kernel_launch(void* const* d_in, const int* in_sizes, int n_in,
                              void* d_out, int out_size, void* d_ws, size_t ws_size,
                              hipStream_t stream) {
    const float* inputs   = (const float*)d_in[0];  // [8, 512, 6000]
    const float* est_mask = (const float*)d_in[1];  // [8, 2, 512, 6000]
    const float* W        = (const float*)d_in[2];  // [512, 16]
    float*       out      = (float*)d_out;          // [8, 2, 48008]

    hipMemsetAsync(out, 0, (size_t)out_size * sizeof(float), stream);

    dim3 grid((KK + KW - 1) / KW, MM);   // (94, 8) = 752 blocks of 512 threads
    decoder_dma_kernel<<<grid, 512, 0, stream>>>(inputs, est_mask, W, out);
}

// Round 6
// 58.875 us; speedup vs baseline: 1.1082x; 1.1082x over previous
//
#include <hip/hip_runtime.h>

// Problem constants: N=512, L=16, HOP=8, M=8, C=2, K=6000
#define NN   512
#define LL   16
#define MM   8
#define CC   2
#define KK   6000
#define TT   ((KK - 1) * 8 + 16)      // 48008
#define KW   128                      // k-columns per block -> 512B granule/row
#define NKB  47                       // ceil(6000/128) real k-blocks
#define NKBP 48                       // padded to 8*6 for XCD banding
#define NCH  16                       // n-rows per chunk (8 waves x 2 rows)
#define NC   (NN / NCH)               // 32 chunks
#define ROWB (KK * 4)                 // 24000 bytes per n-row
#define TENS_B (NCH * KW * 4)         // 8192 B per tensor per buffer
#define BUF_B  (3 * TENS_B)           // 24576 B per buffer

typedef __attribute__((address_space(3))) void       lds_v;
typedef __attribute__((address_space(1))) const void glob_v;

// 512 threads = 8 waves. Lane t handles k = kb*128 + {2t, 2t+1}. Wave-self-
// sufficient DMA pipeline (proven R5): wave wq issues exactly 3
// global_load_lds per chunk (its own 2 rows x 512B x 3 tensors; each instr =
// 64 lanes x 16B = 2 rows x 512B CONTIGUOUS) -> counted s_waitcnt vmcnt(3),
// no barriers in the main loop. XCD banding: bid&7 -> band of 6 consecutive
// kb per XCD so each XCD L2 streams a contiguous 3KB column band.
// Tree-reduce 8 waves -> wave 0, in-register overlap-add (R3 2-k scheme),
// 2-term commutative seam atomics (deterministic).
__global__ __launch_bounds__(512, 4) void decoder_dma_kernel(
    const float* __restrict__ inputs,    // [M, N, K]
    const float* __restrict__ est_mask,  // [M, C, N, K]
    const float* __restrict__ W,         // [N, L]
    float* __restrict__ out)             // [M, C, T], pre-zeroed
{
    __shared__ __align__(16) char lds[2 * BUF_B];   // 48 KB

    // ---- swizzled block -> (kb, m): XCD x owns kb in [x*6, x*6+6) ----
    const int bid = blockIdx.x;          // 0..383
    const int xcd = bid & 7;
    const int s   = bid >> 3;            // 0..47
    const int kb  = xcd * 6 + (s % 6);   // 0..47
    const int m   = s / 6;               // 0..7
    if (kb >= NKB) return;               // 8 padded dummy blocks

    const int tid = threadIdx.x;
    const int t   = tid & 63;                        // lane
    const int wq  = __builtin_amdgcn_readfirstlane(tid >> 6);  // wave 0..7

    // per-lane DMA source: lane covers row (t>>5) of the wave's 2-row pair,
    // 16B slice (t&31) of the row's 512B segment. Clamp for the kb=46 tail
    // (those lanes' results are discarded by the kA<KK guard).
    const int lane_r = t >> 5;
    int cb = kb * 512 + (t & 31) * 16;
    if (cb > ROWB - 16) cb = ROWB - 16;
    const size_t lane_off = (size_t)lane_r * ROWB + cb;

    const char* tb0 = (const char*)inputs   + (size_t)m * NN * ROWB;
    const char* tb1 = (const char*)est_mask + (size_t)(m * CC) * NN * ROWB;
    const char* tb2 = tb1 + (size_t)NN * ROWB;

    char* dst_base = lds + wq * 1024;    // wave's 2-row (1KB) slot per tensor

    auto issue = [&](int c, int bsel) {
        const size_t rowoff = (size_t)(c * NCH + wq * 2) * ROWB + lane_off;
        char* bb = dst_base + bsel * BUF_B;
        __builtin_amdgcn_global_load_lds((glob_v*)(tb0 + rowoff), (lds_v*)(bb),              16, 0, 0);
        __builtin_amdgcn_global_load_lds((glob_v*)(tb1 + rowoff), (lds_v*)(bb + TENS_B),     16, 0, 0);
        __builtin_amdgcn_global_load_lds((glob_v*)(tb2 + rowoff), (lds_v*)(bb + 2 * TENS_B), 16, 0, 0);
    };

    float a0A[LL], a0B[LL], a1A[LL], a1B[LL];        // acc[c][kA/kB][l]
    #pragma unroll
    for (int l = 0; l < LL; ++l) { a0A[l] = 0.f; a0B[l] = 0.f; a1A[l] = 0.f; a1B[l] = 0.f; }

    issue(0, 0);

    for (int c = 0; c < NC; ++c) {
        if (c + 1 < NC) {
            issue(c + 1, (c + 1) & 1);
            // outstanding: [c:3][c+1:3] -> wait <=3 left: c landed, c+1 in flight
            asm volatile("s_waitcnt vmcnt(3)" ::: "memory");
        } else {
            asm volatile("s_waitcnt vmcnt(0)" ::: "memory");
        }
        __builtin_amdgcn_sched_barrier(0);   // no hoisting past the waitcnt

        const char* Lb = lds + (c & 1) * BUF_B + wq * 1024;

        #pragma unroll
        for (int r = 0; r < 2; ++r) {
            const int n = c * NCH + wq * 2 + r;      // wave-uniform -> s_load W
            float wv[LL];
            *reinterpret_cast<float4*>(&wv[0])  = *(const float4*)(W + n * LL + 0);
            *reinterpret_cast<float4*>(&wv[4])  = *(const float4*)(W + n * LL + 4);
            *reinterpret_cast<float4*>(&wv[8])  = *(const float4*)(W + n * LL + 8);
            *reinterpret_cast<float4*>(&wv[12]) = *(const float4*)(W + n * LL + 12);

            const float2 vin = reinterpret_cast<const float2*>(Lb + r * 512)[t];
            const float2 vm0 = reinterpret_cast<const float2*>(Lb + TENS_B + r * 512)[t];
            const float2 vm1 = reinterpret_cast<const float2*>(Lb + 2 * TENS_B + r * 512)[t];
            const float x0A = vin.x * vm0.x, x0B = vin.y * vm0.y;
            const float x1A = vin.x * vm1.x, x1B = vin.y * vm1.y;
            #pragma unroll
            for (int l = 0; l < LL; ++l) {
                a0A[l] = fmaf(x0A, wv[l], a0A[l]);
                a0B[l] = fmaf(x0B, wv[l], a0B[l]);
                a1A[l] = fmaf(x1A, wv[l], a1A[l]);
                a1B[l] = fmaf(x1B, wv[l], a1B[l]);
            }
        }
    }

    // ---- all waves done (own DMA drained); safe to reuse LDS ----
    __syncthreads();

    // ---- tree-reduce 8 waves -> wave 0 (R3 scheme, verified) ----
    float* sm = (float*)lds;
    // act=4, phase c=0 (32 floats/thread, stride 33 -> 2-way free)
    if (wq >= 4) {
        float* d = &sm[((wq - 4) * 64 + t) * 33];
        #pragma unroll
        for (int l = 0; l < LL; ++l) { d[l] = a0A[l]; d[16 + l] = a0B[l]; }
    }
    __syncthreads();
    if (wq < 4) {
        const float* sp = &sm[(wq * 64 + t) * 33];
        #pragma unroll
        for (int l = 0; l < LL; ++l) { a0A[l] += sp[l]; a0B[l] += sp[16 + l]; }
    }
    __syncthreads();
    // act=4, phase c=1
    if (wq >= 4) {
        float* d = &sm[((wq - 4) * 64 + t) * 33];
        #pragma unroll
        for (int l = 0; l < LL; ++l) { d[l] = a1A[l]; d[16 + l] = a1B[l]; }
    }
    __syncthreads();
    if (wq < 4) {
        const float* sp = &sm[(wq * 64 + t) * 33];
        #pragma unroll
        for (int l = 0; l < LL; ++l) { a1A[l] += sp[l]; a1B[l] += sp[16 + l]; }
    }
    __syncthreads();
    // act=2, both c (64 floats/thread, stride 67 -> 2-way free)
    if (wq == 2 || wq == 3) {
        float* d = &sm[((wq - 2) * 64 + t) * 67];
        #pragma unroll
        for (int l = 0; l < LL; ++l) {
            d[l] = a0A[l]; d[16 + l] = a0B[l];
            d[32 + l] = a1A[l]; d[48 + l] = a1B[l];
        }
    }
    __syncthreads();
    if (wq < 2) {
        const float* sp = &sm[(wq * 64 + t) * 67];
        #pragma unroll
        for (int l = 0; l < LL; ++l) {
            a0A[l] += sp[l]; a0B[l] += sp[16 + l];
            a1A[l] += sp[32 + l]; a1B[l] += sp[48 + l];
        }
    }
    __syncthreads();
    // act=1
    if (wq == 1) {
        float* d = &sm[t * 67];
        #pragma unroll
        for (int l = 0; l < LL; ++l) {
            d[l] = a0A[l]; d[16 + l] = a0B[l];
            d[32 + l] = a1A[l]; d[48 + l] = a1B[l];
        }
    }
    __syncthreads();

    if (wq == 0) {
        {
            const float* sp = &sm[t * 67];
            #pragma unroll
            for (int l = 0; l < LL; ++l) {
                a0A[l] += sp[l]; a0B[l] += sp[16 + l];
                a1A[l] += sp[32 + l]; a1B[l] += sp[48 + l];
            }
        }

        // ---- overlap-and-add (R3 2-k scheme) ----
        const int kA = kb * KW + 2 * t;
        // prev-hi for kA comes from lane t-1's kB hi half
        float ph0[8], ph1[8];
        #pragma unroll
        for (int j = 0; j < 8; ++j) {
            ph0[j] = __shfl_up(a0B[8 + j], 1);
            ph1[j] = __shfl_up(a1B[8 + j], 1);
        }

        if (kA < KK) {
            float* o0 = out + ((size_t)m * CC + 0) * TT + 8 * kA;
            float* o1 = out + ((size_t)m * CC + 1) * TT + 8 * kA;

            if (t == 0) {
                // lo of first frame in block: pairs with prev block's hi atomic
                #pragma unroll
                for (int j = 0; j < 8; ++j) {
                    atomicAdd(&o0[j], a0A[j]);
                    atomicAdd(&o1[j], a1A[j]);
                }
            } else {
                #pragma unroll
                for (int j = 0; j < 8; ++j) {
                    o0[j] = a0A[j] + ph0[j];
                    o1[j] = a1A[j] + ph1[j];
                }
            }
            // kB lo: both terms in-lane
            #pragma unroll
            for (int j = 0; j < 8; ++j) {
                o0[8 + j] = a0B[j] + a0A[8 + j];
                o1[8 + j] = a1B[j] + a1A[8 + j];
            }
            // kB hi: consumed by lane t+1 unless block seam / global tail
            const int kB = kA + 1;
            if (t == 63 || kB == KK - 1) {
                #pragma unroll
                for (int j = 0; j < 8; ++j) {
                    atomicAdd(&o0[16 + j], a0B[8 + j]);
                    atomicAdd(&o1[16 + j], a1B[8 + j]);
                }
            }
        }
    }
}

extern "C" void kernel_launch(void* const* d_in, const int* in_sizes, int n_in,
                              void* d_out, int out_size, void* d_ws, size_t ws_size,
                              hipStream_t stream) {
    const float* inputs   = (const float*)d_in[0];  // [8, 512, 6000]
    const float* est_mask = (const float*)d_in[1];  // [8, 2, 512, 6000]
    const float* W        = (const float*)d_in[2];  // [512, 16]
    float*       out      = (float*)d_out;          // [8, 2, 48008]

    hipMemsetAsync(out, 0, (size_t)out_size * sizeof(float), stream);

    decoder_dma_kernel<<<dim3(NKBP * MM), 512, 0, stream>>>(inputs, est_mask, W, out);
}